// Round 1
// 680.564 us; speedup vs baseline: 1.0979x; 1.0979x over previous
//
#include <hip/hip_runtime.h>

// ---- problem constants ----
#define D_DIM 1024
#define E_EXP 8
#define M_DIM 4096
#define N_GRP 8
#define GRP_SZ 1024
#define CAPACITY 256
#define N_TOK (N_GRP * GRP_SZ)                 // 8192 tokens
#define SLOT_ROWS (E_EXP * N_GRP * CAPACITY)   // 16384 expert-slot rows
#define ROWS_PER_E (N_GRP * CAPACITY)          // 2048 rows per expert

typedef _Float16 half8_t __attribute__((ext_vector_type(8)));
typedef float f32x4_t __attribute__((ext_vector_type(4)));

__device__ __forceinline__ void async_copy16(void* lds, const void* gptr) {
  __builtin_amdgcn_global_load_lds(
      (__attribute__((address_space(1))) void*)(void*)(const_cast<void*>(gptr)),
      (__attribute__((address_space(3))) void*)lds,
      16, 0, 0);
}

// fast exact-form tanh-gelu: tanh(w) = 1 - 2/(1+e^{2w}); e^x via v_exp_f32
__device__ __forceinline__ float fast_gelu(float v) {
  float w2 = 1.5957691216057308f * (v + 0.044715f * v * v * v);
  float ex = __expf(w2);
  float t = 1.0f - 2.0f * __builtin_amdgcn_rcpf(1.0f + ex);
  return 0.5f * v * (1.0f + t);
}

// ---------------- router: logits -> softmax -> top2 ----------------
__global__ __launch_bounds__(256)
void router_kernel(const float* __restrict__ x, const float* __restrict__ wr,
                   float* __restrict__ gates, int* __restrict__ tk_idx,
                   float* __restrict__ tk_val) {
  __shared__ __attribute__((aligned(16))) float wrT[E_EXP * D_DIM];
  const int tid = threadIdx.x;
  for (int i = tid; i < E_EXP * D_DIM; i += 256) {
    int d = i >> 3, e = i & 7;
    wrT[e * D_DIM + d] = wr[i];
  }
  __syncthreads();
  const int wv = tid >> 6, lane = tid & 63;
  const int token = blockIdx.x * 4 + wv;   // one wave per token
  const float4* xr = (const float4*)(x + (size_t)token * D_DIM);
  float lg[8] = {0.f, 0.f, 0.f, 0.f, 0.f, 0.f, 0.f, 0.f};
#pragma unroll
  for (int it = 0; it < 4; it++) {
    float4 v = xr[it * 64 + lane];
#pragma unroll
    for (int e = 0; e < 8; e++) {
      float4 w = *(const float4*)&wrT[e * D_DIM + (it * 64 + lane) * 4];
      lg[e] += v.x * w.x + v.y * w.y + v.z * w.z + v.w * w.w;
    }
  }
#pragma unroll
  for (int off = 32; off > 0; off >>= 1) {
#pragma unroll
    for (int e = 0; e < 8; e++) lg[e] += __shfl_xor(lg[e], off, 64);
  }
  if (lane == 0) {
    float mx = lg[0];
#pragma unroll
    for (int e = 1; e < 8; e++) mx = fmaxf(mx, lg[e]);
    float s = 0.f, g[8];
#pragma unroll
    for (int e = 0; e < 8; e++) { g[e] = expf(lg[e] - mx); s += g[e]; }
    float inv = 1.0f / s;
#pragma unroll
    for (int e = 0; e < 8; e++) { g[e] *= inv; gates[(size_t)token * 8 + e] = g[e]; }
    int i0 = 0; float v0 = g[0];
    for (int e = 1; e < 8; e++) if (g[e] > v0) { v0 = g[e]; i0 = e; }
    int i1 = -1; float v1 = -1.f;
    for (int e = 0; e < 8; e++) if (e != i0 && g[e] > v1) { v1 = g[e]; i1 = e; }
    tk_idx[token * 2 + 0] = i0; tk_idx[token * 2 + 1] = i1;
    tk_val[token * 2 + 0] = v0; tk_val[token * 2 + 1] = v1;
  }
}

// ---------------- capacity scan: exact reference semantics ----------------
__global__ void scan_kernel(const int* __restrict__ tk_idx,
                            int* __restrict__ slot_src,
                            int* __restrict__ assign_row) {
  const int g = blockIdx.x;
  const int lane = threadIdx.x;  // 64 threads = 1 wave
  const unsigned long long below = (1ull << lane) - 1ull;
  int ev[32];
#pragma unroll
  for (int k = 0; k < 2; k++)
#pragma unroll
    for (int ch = 0; ch < 16; ch++)
      ev[k * 16 + ch] = tk_idx[((size_t)g * GRP_SZ + ch * 64 + lane) * 2 + k];
  int cnt[8] = {0, 0, 0, 0, 0, 0, 0, 0};
#pragma unroll
  for (int k = 0; k < 2; k++) {
#pragma unroll
    for (int ch = 0; ch < 16; ch++) {
      const int s = ch * 64 + lane;
      const int e = ev[k * 16 + ch];
      int pos = 0;
#pragma unroll
      for (int ee = 0; ee < 8; ee++) {
        unsigned long long m = __ballot(e == ee);
        if (e == ee) pos = cnt[ee] + (int)__popcll(m & below);
        cnt[ee] += (int)__popcll(m);   // unclamped (matches reference prev)
      }
      int row = (pos < CAPACITY) ? ((e * N_GRP + g) * CAPACITY + pos) : -1;
      assign_row[((size_t)g * GRP_SZ + s) * 2 + k] = row;
      if (row >= 0) slot_src[row] = s;
    }
  }
  for (int e = 0; e < 8; e++)
    for (int c = lane; c < CAPACITY; c += 64)
      if (c >= cnt[e]) slot_src[(e * N_GRP + g) * CAPACITY + c] = -1;
}

// ---------------- gather tokens into fp16 expert rows ----------------
__global__ __launch_bounds__(256)
void gather_kernel(const float* __restrict__ x, const int* __restrict__ slot_src,
                   _Float16* __restrict__ A1) {
  const int row = blockIdx.x;
  const int g = (row >> 8) & 7;
  const int t = threadIdx.x;
  const int s = slot_src[row];
  float2* dst = (float2*)(A1 + (size_t)row * D_DIM);
  if (s < 0) { dst[t] = make_float2(0.f, 0.f); return; }
  const float4 v = ((const float4*)x)[((size_t)g * GRP_SZ + s) * (D_DIM / 4) + t];
  union { _Float16 h[4]; float2 f2; } u;
  u.h[0] = (_Float16)v.x; u.h[1] = (_Float16)v.y;
  u.h[2] = (_Float16)v.z; u.h[3] = (_Float16)v.w;
  dst[t] = u.f2;
}

// ---------------- fp32 (E,R,C) -> fp16 (E,C,R) transpose, both weights ----------------
__global__ __launch_bounds__(256)
void transpose_both_kernel(const float* __restrict__ w1, const float* __restrict__ w2,
                           _Float16* __restrict__ w1t, _Float16* __restrict__ w2t) {
  __shared__ float tile[32][33];
  const int z = blockIdx.y;
  const float* sp;
  _Float16* dp;
  int R, C;
  if (z < 8) { sp = w1 + (size_t)z * D_DIM * M_DIM; dp = w1t + (size_t)z * D_DIM * M_DIM; R = D_DIM; C = M_DIM; }
  else       { sp = w2 + (size_t)(z - 8) * M_DIM * D_DIM; dp = w2t + (size_t)(z - 8) * M_DIM * D_DIM; R = M_DIM; C = D_DIM; }
  const int tiles_x = C >> 5;
  const int c0 = (blockIdx.x % tiles_x) * 32, r0 = (blockIdx.x / tiles_x) * 32;
  {
    const int row = threadIdx.x >> 3;        // 0..31
    const int cb = (threadIdx.x & 7) * 4;    // 0,4,..28
    float4 v = *(const float4*)&sp[(size_t)(r0 + row) * C + c0 + cb];
    tile[row][cb + 0] = v.x; tile[row][cb + 1] = v.y;
    tile[row][cb + 2] = v.z; tile[row][cb + 3] = v.w;
  }
  __syncthreads();
  const int cl = threadIdx.x >> 3;   // output row (c)
  const int ch = threadIdx.x & 7;    // chunk of 4 fp16
  union { _Float16 h[4]; float2 f2; } u;
#pragma unroll
  for (int k = 0; k < 4; k++) u.h[k] = (_Float16)tile[ch * 4 + k][cl];
  *(float2*)&dp[(size_t)(c0 + cl) * R + r0 + ch * 4] = u.f2;
}

// ============================================================================
// 256x256 phase-interleaved MFMA GEMM (T2+T3+T4+T5 schedule)
//   C(2048 x N) = A(2048 x K) * BT(N x K)^T  per expert (blockIdx.z)
// 8 waves (2M x 4N), per-wave 128x64 output, BK=64 split into two K=32 units.
// LDS = 128 KiB dynamic: per operand a ring of 4 units (256rows x 32K fp16,
// 16 KiB each; slot = ((tile&1)*2 + khalf)). Staging unit u = 4t+j with
// j = {A.k0, B.k0, A.k1, B.k1} is issued at phase (u-5) -> lands >=4 phases
// before first read; its slot's previous tenant had its last read >=1
// barrier-separated phase before issue.  Boundary waits are counted:
// s_waitcnt vmcnt(6) (3 units = 6 loads stay in flight), never 0 except tail.
// Per phase: {4-or-8 ds_read_b128 ; stage 1 unit (2 global_load_lds_dwordx4) ;
//             s_barrier ; setprio(1) ; 16 MFMA ; setprio(0) ; [vmcnt] ; s_barrier}
// LDS swizzle: row-pair layout [128][8 chunks of 16B], stored chunk =
// (((row&1)<<2)|kchunk) ^ ((row>>1)&7); applied to the *global* source address
// during staging (linear global_load_lds dest), and to the ds_read address.
// Fragment ds_read_b128 is 2-way bank-aliased (free).
// EPI==1: gelu(acc+bias) -> per-wave LDS restage -> coalesced fp16 store (H).
// EPI==2: acc+bias -> fp32 direct store (ye).
// ============================================================================
template <int KDIM, int NDIM, int EPI>
__global__ __launch_bounds__(512, 2)
void gemm256_kernel(const _Float16* __restrict__ Aall,
                    const _Float16* __restrict__ BTall,
                    const float* __restrict__ biasAll,
                    void* __restrict__ CoutAll) {
  constexpr int NT = KDIM / 64;
  constexpr int NXT = ROWS_PER_E / 256;   // 8
  constexpr int NYT = NDIM / 256;
  constexpr int NB = NXT * NYT;
  static_assert(NXT == 8 && (NB % 8) == 0 && NT >= 4, "geometry");

  extern __shared__ __attribute__((aligned(16))) _Float16 smem[];
  _Float16* lA = smem;            // 4 slots x 8192 els (64 KiB)
  _Float16* lB = smem + 32768;    // 4 slots x 8192 els (64 KiB)

  const int e = blockIdx.z;
  const _Float16* A  = Aall  + (size_t)e * ROWS_PER_E * KDIM;
  const _Float16* BT = BTall + (size_t)e * NDIM * KDIM;
  const float* bias  = biasAll + (size_t)e * NDIM;

  // bijective XCD swizzle (NB % 8 == 0); xt fast -> neighbors share B slab
  const int bswz = (blockIdx.x & 7) * (NB >> 3) + (blockIdx.x >> 3);
  const int xt = bswz & (NXT - 1);
  const int yt = bswz >> 3;
  const int rowblk = xt * 256;
  const int colblk = yt * 256;

  const int tid = threadIdx.x;
  const int wave = tid >> 6, lane = tid & 63;
  const int wm = wave >> 2, wn = wave & 3;          // 2M x 4N wave grid
  const int quad = lane >> 4, ln = lane & 15;

  // ---- staging geometry (inverse swizzle on the global source) ----
  const int schunk = (tid & 7) ^ ((tid >> 3) & 7);
  const int rowA = ((tid >> 3) << 1) + (schunk >> 2);   // 0..127
  const int colA = (schunk & 3) << 3;                   // 0,8,16,24
  const _Float16* baseA = A  + (size_t)(rowblk + rowA) * KDIM + colA;
  const _Float16* baseB = BT + (size_t)(colblk + rowA) * KDIM + colA;
  const int ldsW = wave * 512;  // wave-uniform; HW adds lane*16B

  auto stage_unit = [&](int u) {
    const int tu = u >> 2;
    const int j = u & 3;                   // 0:A.k0 1:B.k0 2:A.k1 3:B.k1
    const int ks = j >> 1;
    const int koff = tu * 64 + ks * 32;
    const int slot = ((tu & 1) * 2 + ks) * 8192 + ldsW;
    if ((j & 1) == 0) {
      const _Float16* g = baseA + koff;
      async_copy16(lA + slot, g);
      async_copy16(lA + slot + 4096, g + (size_t)128 * KDIM);
    } else {
      const _Float16* g = baseB + koff;
      async_copy16(lB + slot, g);
      async_copy16(lB + slot + 4096, g + (size_t)128 * KDIM);
    }
  };

  // ---- fragment read offsets (within a unit slot, elements) ----
  // row = <frag-base> + ln maps to (rowpair = base/2 + (ln>>1), row&1 = ln&1)
  const int swc = (((ln & 1) << 2) | quad) ^ (ln >> 1);
  int offA[8], offB[4];
#pragma unroll
  for (int i = 0; i < 8; ++i)
    offA[i] = (wm * 64 + i * 8 + (ln >> 1)) * 64 + swc * 8;
#pragma unroll
  for (int j = 0; j < 4; ++j)
    offB[j] = (wn * 32 + j * 8 + (ln >> 1)) * 64 + swc * 8;

  f32x4_t acc[8][4] = {};

  // prologue: units 0..4 (tile0 complete + tile1 A.k0), then wait units 0,1
#pragma unroll
  for (int u = 0; u < 5; ++u) stage_unit(u);
  asm volatile("s_waitcnt vmcnt(6)" ::: "memory");
  __builtin_amdgcn_s_barrier();

  for (int t = 0; t < NT; ++t) {
    const int bufo = (t & 1) * 2 * 8192;
    half8_t bf[4];
#pragma unroll
    for (int p = 0; p < 4; ++p) {
      const int ks = p >> 1;
      const int ms = (p & 1) * 4;
      const _Float16* Ap = lA + bufo + ks * 8192;
      const _Float16* Bp = lB + bufo + ks * 8192;
      half8_t af[4];
#pragma unroll
      for (int i = 0; i < 4; ++i) af[i] = *(const half8_t*)&Ap[offA[ms + i]];
      if ((p & 1) == 0) {
#pragma unroll
        for (int j = 0; j < 4; ++j) bf[j] = *(const half8_t*)&Bp[offB[j]];
      }
      {
        const int u = 4 * t + p + 5;        // staging stream, 5 phases ahead
        if (u < 4 * NT) stage_unit(u);
      }
      __builtin_amdgcn_s_barrier();
      __builtin_amdgcn_s_setprio(1);
#pragma unroll
      for (int i = 0; i < 4; ++i)
#pragma unroll
        for (int j = 0; j < 4; ++j)
          acc[ms + i][j] = __builtin_amdgcn_mfma_f32_16x16x32_f16(
              af[i], bf[j], acc[ms + i][j], 0, 0, 0);
      __builtin_amdgcn_s_setprio(0);
      // counted boundary waits: need next 2 units landed, leave 3 in flight
      if (p == 1) {
        if (t == NT - 1) asm volatile("s_waitcnt vmcnt(0)" ::: "memory");
        else             asm volatile("s_waitcnt vmcnt(6)" ::: "memory");
      } else if (p == 3) {
        if (t == NT - 2)     asm volatile("s_waitcnt vmcnt(4)" ::: "memory");
        else if (t < NT - 2) asm volatile("s_waitcnt vmcnt(6)" ::: "memory");
      }
      __builtin_amdgcn_s_barrier();
    }
  }

  __syncthreads();   // full drain; LDS repurposed for epilogue staging

  float bcol[4];
#pragma unroll
  for (int j = 0; j < 4; ++j) bcol[j] = bias[colblk + wn * 64 + j * 16 + ln];

  if constexpr (EPI == 1) {
    _Float16* Cc = (_Float16*)CoutAll + (size_t)e * ROWS_PER_E * NDIM;
    _Float16* eb = smem + wave * 1280;       // per-wave 16x72 fp16, no barriers
#pragma unroll
    for (int i = 0; i < 8; ++i) {
#pragma unroll
      for (int j = 0; j < 4; ++j)
#pragma unroll
        for (int r = 0; r < 4; ++r)
          eb[(quad * 4 + r) * 72 + j * 16 + ln] =
              (_Float16)fast_gelu(acc[i][j][r] + bcol[j]);
#pragma unroll
      for (int q = 0; q < 2; ++q) {
        const int rl = q * 8 + (lane >> 3);
        const int ch = lane & 7;
        float4 vv = *(const float4*)&eb[rl * 72 + ch * 8];
        *(float4*)&Cc[(size_t)(rowblk + wm * 128 + i * 16 + rl) * NDIM +
                      colblk + wn * 64 + ch * 8] = vv;
      }
    }
  } else {
    float* Cc = (float*)CoutAll + (size_t)e * ROWS_PER_E * NDIM;
#pragma unroll
    for (int i = 0; i < 8; ++i)
#pragma unroll
      for (int j = 0; j < 4; ++j)
#pragma unroll
        for (int r = 0; r < 4; ++r)
          Cc[(size_t)(rowblk + wm * 128 + i * 16 + quad * 4 + r) * NDIM +
             colblk + wn * 64 + j * 16 + ln] = acc[i][j][r] + bcol[j];
  }
}

// ---------------- gated combine scatter ----------------
__global__ __launch_bounds__(256)
void combine_kernel(const float* __restrict__ ye, const int* __restrict__ assign_row,
                    const float* __restrict__ tk_val, float* __restrict__ out) {
  const int t = blockIdx.x;
  const int d = threadIdx.x;
  const int r0 = assign_row[t * 2 + 0];
  const int r1 = assign_row[t * 2 + 1];
  const float g0 = tk_val[t * 2 + 0];
  const float g1 = tk_val[t * 2 + 1];
  const float4* y4 = (const float4*)ye;
  float4 v = make_float4(0.f, 0.f, 0.f, 0.f);
  if (r0 >= 0) {
    float4 a = y4[(size_t)r0 * (D_DIM / 4) + d];
    v.x += g0 * a.x; v.y += g0 * a.y; v.z += g0 * a.z; v.w += g0 * a.w;
  }
  if (r1 >= 0) {
    float4 a = y4[(size_t)r1 * (D_DIM / 4) + d];
    v.x += g1 * a.x; v.y += g1 * a.y; v.z += g1 * a.z; v.w += g1 * a.w;
  }
  ((float4*)out)[(size_t)t * (D_DIM / 4) + d] = v;
}

// ---------------- aux: stage 1 (64 blocks, one per (g,e)) ----------------
__global__ __launch_bounds__(256)
void aux1_kernel(const float* __restrict__ gates, float* __restrict__ imp) {
  const int g = blockIdx.x >> 3, e = blockIdx.x & 7;
  const int tid = threadIdx.x, lane = tid & 63, wave = tid >> 6;
  float s = 0.f;
  for (int t = tid; t < GRP_SZ; t += 256)
    s += gates[((size_t)g * GRP_SZ + t) * 8 + e];
#pragma unroll
  for (int off = 32; off > 0; off >>= 1) s += __shfl_xor(s, off, 64);
  __shared__ float ws4[4];
  if (lane == 0) ws4[wave] = s;
  __syncthreads();
  if (tid == 0) imp[blockIdx.x] = ws4[0] + ws4[1] + ws4[2] + ws4[3];
}

// ---------------- aux: stage 2 (tiny) ----------------
__global__ void aux2_kernel(const float* __restrict__ imp, float* __restrict__ aux_out) {
  const int t = threadIdx.x;  // 64
  __shared__ float cvS[8];
  if (t < 8) {
    float mean = 0.f;
    for (int k = 0; k < 8; k++) mean += imp[t * 8 + k];
    mean *= 0.125f;
    float var = 0.f;
    for (int k = 0; k < 8; k++) { float dd = imp[t * 8 + k] - mean; var += dd * dd; }
    var *= 0.125f;
    cvS[t] = var / (mean * mean);
  }
  __syncthreads();
  if (t == 0) {
    float a = 0.f;
    for (int k = 0; k < 8; k++) a += cvS[k];
    aux_out[0] = a * 0.125f;
  }
}

extern "C" void kernel_launch(void* const* d_in, const int* in_sizes, int n_in,
                              void* d_out, int out_size, void* d_ws, size_t ws_size,
                              hipStream_t stream) {
  const float* x  = (const float*)d_in[0];
  const float* wr = (const float*)d_in[1];
  const float* w1 = (const float*)d_in[2];
  const float* b1 = (const float*)d_in[3];
  const float* w2 = (const float*)d_in[4];
  const float* b2 = (const float*)d_in[5];
  float* out = (float*)d_out;

  char* ws = (char*)d_ws;
  size_t off = 0;
  auto alloc = [&](size_t bytes) -> void* {
    void* p = ws + off;
    off += (bytes + 255) & ~(size_t)255;
    return p;
  };
  float*     gates      = (float*)alloc((size_t)N_TOK * 8 * 4);
  int*       tk_idx     = (int*)  alloc((size_t)N_TOK * 2 * 4);
  float*     tk_val     = (float*)alloc((size_t)N_TOK * 2 * 4);
  int*       assign_row = (int*)  alloc((size_t)N_TOK * 2 * 4);
  int*       slot_src   = (int*)  alloc((size_t)SLOT_ROWS * 4);
  float*     imp        = (float*)alloc(64 * 4);
  _Float16*  A1  = (_Float16*)alloc((size_t)SLOT_ROWS * D_DIM * 2);
  _Float16*  w1t = (_Float16*)alloc((size_t)E_EXP * M_DIM * D_DIM * 2);
  _Float16*  w2t = (_Float16*)alloc((size_t)E_EXP * D_DIM * M_DIM * 2);
  _Float16*  H   = (_Float16*)alloc((size_t)SLOT_ROWS * M_DIM * 2);
  float*     ye  = (float*)   alloc((size_t)SLOT_ROWS * D_DIM * 4);
  if (off > ws_size) return;

  router_kernel<<<N_TOK / 4, 256, 0, stream>>>(x, wr, gates, tk_idx, tk_val);
  scan_kernel<<<N_GRP, 64, 0, stream>>>(tk_idx, slot_src, assign_row);
  gather_kernel<<<SLOT_ROWS, 256, 0, stream>>>(x, slot_src, A1);
  transpose_both_kernel<<<dim3(4096, 16), 256, 0, stream>>>(w1, w2, w1t, w2t);
  gemm256_kernel<D_DIM, M_DIM, 1>
      <<<dim3((ROWS_PER_E / 256) * (M_DIM / 256), 1, E_EXP), 512, 131072, stream>>>(A1, w1t, b1, H);
  gemm256_kernel<M_DIM, D_DIM, 2>
      <<<dim3((ROWS_PER_E / 256) * (D_DIM / 256), 1, E_EXP), 512, 131072, stream>>>(H, w2t, b2, ye);
  combine_kernel<<<N_TOK, 256, 0, stream>>>(ye, assign_row, tk_val, out);
  aux1_kernel<<<64, 256, 0, stream>>>(gates, imp);
  aux2_kernel<<<1, 64, 0, stream>>>(imp, out + (size_t)N_TOK * D_DIM);
}

// Round 2
// 672.488 us; speedup vs baseline: 1.1111x; 1.0120x over previous
//
#include <hip/hip_runtime.h>

// ---- problem constants ----
#define D_DIM 1024
#define E_EXP 8
#define M_DIM 4096
#define N_GRP 8
#define GRP_SZ 1024
#define CAPACITY 256
#define N_TOK (N_GRP * GRP_SZ)                 // 8192 tokens
#define SLOT_ROWS (E_EXP * N_GRP * CAPACITY)   // 16384 expert-slot rows
#define ROWS_PER_E (N_GRP * CAPACITY)          // 2048 rows per expert

typedef _Float16 half8_t __attribute__((ext_vector_type(8)));
typedef float f32x4_t __attribute__((ext_vector_type(4)));

__device__ __forceinline__ void async_copy16(void* lds, const void* gptr) {
  __builtin_amdgcn_global_load_lds(
      (__attribute__((address_space(1))) void*)(void*)(const_cast<void*>(gptr)),
      (__attribute__((address_space(3))) void*)lds,
      16, 0, 0);
}

// fast exact-form tanh-gelu: tanh(w) = 1 - 2/(1+e^{2w}); e^x via v_exp_f32
__device__ __forceinline__ float fast_gelu(float v) {
  float w2 = 1.5957691216057308f * (v + 0.044715f * v * v * v);
  float ex = __expf(w2);
  float t = 1.0f - 2.0f * __builtin_amdgcn_rcpf(1.0f + ex);
  return 0.5f * v * (1.0f + t);
}

// ---------------- router: logits -> softmax -> top2 ----------------
__global__ __launch_bounds__(256)
void router_kernel(const float* __restrict__ x, const float* __restrict__ wr,
                   float* __restrict__ gates, int* __restrict__ tk_idx,
                   float* __restrict__ tk_val) {
  __shared__ __attribute__((aligned(16))) float wrT[E_EXP * D_DIM];
  const int tid = threadIdx.x;
  for (int i = tid; i < E_EXP * D_DIM; i += 256) {
    int d = i >> 3, e = i & 7;
    wrT[e * D_DIM + d] = wr[i];
  }
  __syncthreads();
  const int wv = tid >> 6, lane = tid & 63;
  const int token = blockIdx.x * 4 + wv;   // one wave per token
  const float4* xr = (const float4*)(x + (size_t)token * D_DIM);
  float lg[8] = {0.f, 0.f, 0.f, 0.f, 0.f, 0.f, 0.f, 0.f};
#pragma unroll
  for (int it = 0; it < 4; it++) {
    float4 v = xr[it * 64 + lane];
#pragma unroll
    for (int e = 0; e < 8; e++) {
      float4 w = *(const float4*)&wrT[e * D_DIM + (it * 64 + lane) * 4];
      lg[e] += v.x * w.x + v.y * w.y + v.z * w.z + v.w * w.w;
    }
  }
#pragma unroll
  for (int off = 32; off > 0; off >>= 1) {
#pragma unroll
    for (int e = 0; e < 8; e++) lg[e] += __shfl_xor(lg[e], off, 64);
  }
  if (lane == 0) {
    float mx = lg[0];
#pragma unroll
    for (int e = 1; e < 8; e++) mx = fmaxf(mx, lg[e]);
    float s = 0.f, g[8];
#pragma unroll
    for (int e = 0; e < 8; e++) { g[e] = expf(lg[e] - mx); s += g[e]; }
    float inv = 1.0f / s;
#pragma unroll
    for (int e = 0; e < 8; e++) { g[e] *= inv; gates[(size_t)token * 8 + e] = g[e]; }
    int i0 = 0; float v0 = g[0];
    for (int e = 1; e < 8; e++) if (g[e] > v0) { v0 = g[e]; i0 = e; }
    int i1 = -1; float v1 = -1.f;
    for (int e = 0; e < 8; e++) if (e != i0 && g[e] > v1) { v1 = g[e]; i1 = e; }
    tk_idx[token * 2 + 0] = i0; tk_idx[token * 2 + 1] = i1;
    tk_val[token * 2 + 0] = v0; tk_val[token * 2 + 1] = v1;
  }
}

// ---------------- capacity scan: exact reference semantics ----------------
__global__ void scan_kernel(const int* __restrict__ tk_idx,
                            int* __restrict__ slot_src,
                            int* __restrict__ assign_row) {
  const int g = blockIdx.x;
  const int lane = threadIdx.x;  // 64 threads = 1 wave
  const unsigned long long below = (1ull << lane) - 1ull;
  int ev[32];
#pragma unroll
  for (int k = 0; k < 2; k++)
#pragma unroll
    for (int ch = 0; ch < 16; ch++)
      ev[k * 16 + ch] = tk_idx[((size_t)g * GRP_SZ + ch * 64 + lane) * 2 + k];
  int cnt[8] = {0, 0, 0, 0, 0, 0, 0, 0};
#pragma unroll
  for (int k = 0; k < 2; k++) {
#pragma unroll
    for (int ch = 0; ch < 16; ch++) {
      const int s = ch * 64 + lane;
      const int e = ev[k * 16 + ch];
      int pos = 0;
#pragma unroll
      for (int ee = 0; ee < 8; ee++) {
        unsigned long long m = __ballot(e == ee);
        if (e == ee) pos = cnt[ee] + (int)__popcll(m & below);
        cnt[ee] += (int)__popcll(m);   // unclamped (matches reference prev)
      }
      int row = (pos < CAPACITY) ? ((e * N_GRP + g) * CAPACITY + pos) : -1;
      assign_row[((size_t)g * GRP_SZ + s) * 2 + k] = row;
      if (row >= 0) slot_src[row] = s;
    }
  }
  for (int e = 0; e < 8; e++)
    for (int c = lane; c < CAPACITY; c += 64)
      if (c >= cnt[e]) slot_src[(e * N_GRP + g) * CAPACITY + c] = -1;
}

// ---------------- gather tokens into fp16 expert rows ----------------
__global__ __launch_bounds__(256)
void gather_kernel(const float* __restrict__ x, const int* __restrict__ slot_src,
                   _Float16* __restrict__ A1) {
  const int row = blockIdx.x;
  const int g = (row >> 8) & 7;
  const int t = threadIdx.x;
  const int s = slot_src[row];
  float2* dst = (float2*)(A1 + (size_t)row * D_DIM);
  if (s < 0) { dst[t] = make_float2(0.f, 0.f); return; }
  const float4 v = ((const float4*)x)[((size_t)g * GRP_SZ + s) * (D_DIM / 4) + t];
  union { _Float16 h[4]; float2 f2; } u;
  u.h[0] = (_Float16)v.x; u.h[1] = (_Float16)v.y;
  u.h[2] = (_Float16)v.z; u.h[3] = (_Float16)v.w;
  dst[t] = u.f2;
}

// ---------------- fp32 (E,R,C) -> fp16 (E,C,R) transpose, both weights ----------------
__global__ __launch_bounds__(256)
void transpose_both_kernel(const float* __restrict__ w1, const float* __restrict__ w2,
                           _Float16* __restrict__ w1t, _Float16* __restrict__ w2t) {
  __shared__ float tile[32][33];
  const int z = blockIdx.y;
  const float* sp;
  _Float16* dp;
  int R, C;
  if (z < 8) { sp = w1 + (size_t)z * D_DIM * M_DIM; dp = w1t + (size_t)z * D_DIM * M_DIM; R = D_DIM; C = M_DIM; }
  else       { sp = w2 + (size_t)(z - 8) * M_DIM * D_DIM; dp = w2t + (size_t)(z - 8) * M_DIM * D_DIM; R = M_DIM; C = D_DIM; }
  const int tiles_x = C >> 5;
  const int c0 = (blockIdx.x % tiles_x) * 32, r0 = (blockIdx.x / tiles_x) * 32;
  {
    const int row = threadIdx.x >> 3;        // 0..31
    const int cb = (threadIdx.x & 7) * 4;    // 0,4,..28
    float4 v = *(const float4*)&sp[(size_t)(r0 + row) * C + c0 + cb];
    tile[row][cb + 0] = v.x; tile[row][cb + 1] = v.y;
    tile[row][cb + 2] = v.z; tile[row][cb + 3] = v.w;
  }
  __syncthreads();
  const int cl = threadIdx.x >> 3;   // output row (c)
  const int ch = threadIdx.x & 7;    // chunk of 4 fp16
  union { _Float16 h[4]; float2 f2; } u;
#pragma unroll
  for (int k = 0; k < 4; k++) u.h[k] = (_Float16)tile[ch * 4 + k][cl];
  *(float2*)&dp[(size_t)(c0 + cl) * R + r0 + ch * 4] = u.f2;
}

// ============================================================================
// 256x256 phase-interleaved MFMA GEMM, one-phase FRAGMENT READ-AHEAD.
// Phase p issues ds_reads for phase p+1's MFMA and computes with registers
// read in phase p-1 -> the lgkm wait before MFMA covers reads issued a full
// phase earlier (~zero stall); LDS service overlaps the matrix bursts.
// Fragment sets are explicitly named (afE/afO/bfE/bfO) for static indexing.
// Staging lead = 6 units (prologue stages 6), counted vmcnt(6) at p0/p2 only.
// Hazard algebra (verified): overwrite of slot X is issued >=1 barrier-
// separated phase after X's last read is lgkm-consumed; reads outstanding at
// any stage-issue target a different slot; tail waits vmcnt(0)@p0 of t=NT-1,
// vmcnt(4)@p2 of t=NT-2.
// Per phase: {4-or-8 ds_read_b128 (next frags) ; stage 1 unit ; [vmcnt] ;
//             s_barrier ; setprio(1) ; 16 MFMA (prev frags) ; setprio(0) ;
//             s_barrier}, sched_barrier(0) pinned at each s_barrier.
// LDS swizzle: row-pair layout, stored chunk = (((row&1)<<2)|kchunk)^((row>>1)&7),
// applied to the *global* source during staging (linear global_load_lds dest)
// and to the ds_read address.  EPI==1: gelu->fp16 LDS restage. EPI==2:
// fp32 per-wave LDS restage -> float4 stores.
// ============================================================================
template <int KDIM, int NDIM, int EPI>
__global__ __launch_bounds__(512, 2)
void gemm256_kernel(const _Float16* __restrict__ Aall,
                    const _Float16* __restrict__ BTall,
                    const float* __restrict__ biasAll,
                    void* __restrict__ CoutAll) {
  constexpr int NT = KDIM / 64;
  constexpr int NXT = ROWS_PER_E / 256;   // 8
  constexpr int NYT = NDIM / 256;
  constexpr int NB = NXT * NYT;
  static_assert(NXT == 8 && (NB % 8) == 0 && NT >= 4, "geometry");

  extern __shared__ __attribute__((aligned(16))) _Float16 smem[];
  _Float16* lA = smem;            // 4 slots x 8192 els (64 KiB)
  _Float16* lB = smem + 32768;    // 4 slots x 8192 els (64 KiB)

  const int e = blockIdx.z;
  const _Float16* A  = Aall  + (size_t)e * ROWS_PER_E * KDIM;
  const _Float16* BT = BTall + (size_t)e * NDIM * KDIM;
  const float* bias  = biasAll + (size_t)e * NDIM;

  // bijective XCD swizzle (NB % 8 == 0); xt fast -> neighbors share B slab
  const int bswz = (blockIdx.x & 7) * (NB >> 3) + (blockIdx.x >> 3);
  const int xt = bswz & (NXT - 1);
  const int yt = bswz >> 3;
  const int rowblk = xt * 256;
  const int colblk = yt * 256;

  const int tid = threadIdx.x;
  const int wave = tid >> 6, lane = tid & 63;
  const int wm = wave >> 2, wn = wave & 3;          // 2M x 4N wave grid
  const int quad = lane >> 4, ln = lane & 15;

  // ---- staging geometry (inverse swizzle on the global source) ----
  const int schunk = (tid & 7) ^ ((tid >> 3) & 7);
  const int rowA = ((tid >> 3) << 1) + (schunk >> 2);   // 0..127
  const int colA = (schunk & 3) << 3;                   // 0,8,16,24
  const _Float16* baseA = A  + (size_t)(rowblk + rowA) * KDIM + colA;
  const _Float16* baseB = BT + (size_t)(colblk + rowA) * KDIM + colA;
  const int ldsW = wave * 512;  // wave-uniform; HW adds lane*16B

  auto stage = [&](int tu, int ks, int isB) {
    if (tu >= NT) return;
    const int slot = ((tu & 1) * 2 + ks) * 8192 + ldsW;
    const int koff = tu * 64 + ks * 32;
    if (!isB) {
      const _Float16* g = baseA + koff;
      async_copy16(lA + slot, g);
      async_copy16(lA + slot + 4096, g + (size_t)128 * KDIM);
    } else {
      const _Float16* g = baseB + koff;
      async_copy16(lB + slot, g);
      async_copy16(lB + slot + 4096, g + (size_t)128 * KDIM);
    }
  };

  // ---- fragment read offsets (within a unit slot, elements) ----
  const int swc = (((ln & 1) << 2) | quad) ^ (ln >> 1);
  int offA[8], offB[4];
#pragma unroll
  for (int i = 0; i < 8; ++i)
    offA[i] = (wm * 64 + i * 8 + (ln >> 1)) * 64 + swc * 8;
#pragma unroll
  for (int j = 0; j < 4; ++j)
    offB[j] = (wn * 32 + j * 8 + (ln >> 1)) * 64 + swc * 8;

  half8_t afE[4], afO[4], bfE[4], bfO[4];
  f32x4_t acc[8][4] = {};

  // prologue: 6 units (tile0 complete + tile1 k0), wait units 0,1 landed
  stage(0, 0, 0); stage(0, 0, 1); stage(0, 1, 0); stage(0, 1, 1);
  stage(1, 0, 0); stage(1, 0, 1);
  asm volatile("s_waitcnt vmcnt(8)" ::: "memory");
  __builtin_amdgcn_s_barrier();
#pragma unroll
  for (int i = 0; i < 4; ++i) afE[i] = *(const half8_t*)&lA[offA[i]];
#pragma unroll
  for (int j = 0; j < 4; ++j) bfE[j] = *(const half8_t*)&lB[offB[j]];

#define MFMA_CLUSTER(MS, AF, BF)                                               \
  __builtin_amdgcn_s_setprio(1);                                               \
  _Pragma("unroll")                                                            \
  for (int i = 0; i < 4; ++i)                                                  \
    _Pragma("unroll")                                                          \
    for (int j = 0; j < 4; ++j)                                                \
      acc[(MS) + i][j] = __builtin_amdgcn_mfma_f32_16x16x32_f16(               \
          AF[i], BF[j], acc[(MS) + i][j], 0, 0, 0);                            \
  __builtin_amdgcn_s_setprio(0);

  for (int t = 0; t < NT; ++t) {
    const int par = (t & 1) * 2;
    const int parn = ((t + 1) & 1) * 2;
    const _Float16* A0 = lA + par * 8192;          // A(t, k0)
    const _Float16* A1 = lA + (par + 1) * 8192;    // A(t, k1)
    const _Float16* B1 = lB + (par + 1) * 8192;    // B(t, k1)
    const _Float16* A0n = lA + parn * 8192;        // A(t+1, k0)
    const _Float16* B0n = lB + parn * 8192;        // B(t+1, k0)

    // ---- phase 0: read A(t,k0) ms4 ; compute (afE,bfE) = k0 x ms0 ----
#pragma unroll
    for (int i = 0; i < 4; ++i) afO[i] = *(const half8_t*)&A0[offA[4 + i]];
    stage(t + 1, 1, 0);
    if (t < NT - 1) asm volatile("s_waitcnt vmcnt(6)" ::: "memory");
    else            asm volatile("s_waitcnt vmcnt(0)" ::: "memory");
    __builtin_amdgcn_sched_barrier(0);
    __builtin_amdgcn_s_barrier();
    MFMA_CLUSTER(0, afE, bfE)
    __builtin_amdgcn_sched_barrier(0);
    __builtin_amdgcn_s_barrier();

    // ---- phase 1: read A(t,k1) ms0 + B(t,k1) ; compute (afO,bfE) ----
#pragma unroll
    for (int i = 0; i < 4; ++i) afE[i] = *(const half8_t*)&A1[offA[i]];
#pragma unroll
    for (int j = 0; j < 4; ++j) bfO[j] = *(const half8_t*)&B1[offB[j]];
    stage(t + 1, 1, 1);
    __builtin_amdgcn_sched_barrier(0);
    __builtin_amdgcn_s_barrier();
    MFMA_CLUSTER(4, afO, bfE)
    __builtin_amdgcn_sched_barrier(0);
    __builtin_amdgcn_s_barrier();

    // ---- phase 2: read A(t,k1) ms4 ; compute (afE,bfO) = k1 x ms0 ----
#pragma unroll
    for (int i = 0; i < 4; ++i) afO[i] = *(const half8_t*)&A1[offA[4 + i]];
    stage(t + 2, 0, 0);
    if (t < NT - 2)      asm volatile("s_waitcnt vmcnt(6)" ::: "memory");
    else if (t == NT - 2) asm volatile("s_waitcnt vmcnt(4)" ::: "memory");
    __builtin_amdgcn_sched_barrier(0);
    __builtin_amdgcn_s_barrier();
    MFMA_CLUSTER(0, afE, bfO)
    __builtin_amdgcn_sched_barrier(0);
    __builtin_amdgcn_s_barrier();

    // ---- phase 3: read A(t+1,k0) ms0 + B(t+1,k0) ; compute (afO,bfO) ----
    if (t < NT - 1) {
#pragma unroll
      for (int i = 0; i < 4; ++i) afE[i] = *(const half8_t*)&A0n[offA[i]];
#pragma unroll
      for (int j = 0; j < 4; ++j) bfE[j] = *(const half8_t*)&B0n[offB[j]];
    }
    stage(t + 2, 0, 1);
    __builtin_amdgcn_sched_barrier(0);
    __builtin_amdgcn_s_barrier();
    MFMA_CLUSTER(4, afO, bfO)
    __builtin_amdgcn_sched_barrier(0);
    __builtin_amdgcn_s_barrier();
  }
#undef MFMA_CLUSTER

  __syncthreads();   // full drain; LDS repurposed for epilogue staging

  float bcol[4];
#pragma unroll
  for (int j = 0; j < 4; ++j) bcol[j] = bias[colblk + wn * 64 + j * 16 + ln];

  if constexpr (EPI == 1) {
    _Float16* Cc = (_Float16*)CoutAll + (size_t)e * ROWS_PER_E * NDIM;
    _Float16* eb = smem + wave * 1280;       // per-wave 16x72 fp16, no barriers
#pragma unroll
    for (int i = 0; i < 8; ++i) {
#pragma unroll
      for (int j = 0; j < 4; ++j)
#pragma unroll
        for (int r = 0; r < 4; ++r)
          eb[(quad * 4 + r) * 72 + j * 16 + ln] =
              (_Float16)fast_gelu(acc[i][j][r] + bcol[j]);
#pragma unroll
      for (int q = 0; q < 2; ++q) {
        const int rl = q * 8 + (lane >> 3);
        const int ch = lane & 7;
        float4 vv = *(const float4*)&eb[rl * 72 + ch * 8];
        *(float4*)&Cc[(size_t)(rowblk + wm * 128 + i * 16 + rl) * NDIM +
                      colblk + wn * 64 + ch * 8] = vv;
      }
    }
  } else {
    float* Cc = (float*)CoutAll + (size_t)e * ROWS_PER_E * NDIM;
    float* ebf = (float*)smem + wave * 1088;  // per-wave 16x68 fp32
#pragma unroll
    for (int i = 0; i < 8; ++i) {
#pragma unroll
      for (int j = 0; j < 4; ++j)
#pragma unroll
        for (int r = 0; r < 4; ++r)
          ebf[(quad * 4 + r) * 68 + j * 16 + ln] = acc[i][j][r] + bcol[j];
      const int rl = lane >> 2;
      const int ch = lane & 3;
#pragma unroll
      for (int q = 0; q < 4; ++q) {
        float4 vv = *(const float4*)&ebf[rl * 68 + q * 16 + ch * 4];
        *(float4*)&Cc[(size_t)(rowblk + wm * 128 + i * 16 + rl) * NDIM +
                      colblk + wn * 64 + q * 16 + ch * 4] = vv;
      }
    }
  }
}

// ---------------- gated combine scatter ----------------
__global__ __launch_bounds__(256)
void combine_kernel(const float* __restrict__ ye, const int* __restrict__ assign_row,
                    const float* __restrict__ tk_val, float* __restrict__ out) {
  const int t = blockIdx.x;
  const int d = threadIdx.x;
  const int r0 = assign_row[t * 2 + 0];
  const int r1 = assign_row[t * 2 + 1];
  const float g0 = tk_val[t * 2 + 0];
  const float g1 = tk_val[t * 2 + 1];
  const float4* y4 = (const float4*)ye;
  float4 v = make_float4(0.f, 0.f, 0.f, 0.f);
  if (r0 >= 0) {
    float4 a = y4[(size_t)r0 * (D_DIM / 4) + d];
    v.x += g0 * a.x; v.y += g0 * a.y; v.z += g0 * a.z; v.w += g0 * a.w;
  }
  if (r1 >= 0) {
    float4 a = y4[(size_t)r1 * (D_DIM / 4) + d];
    v.x += g1 * a.x; v.y += g1 * a.y; v.z += g1 * a.z; v.w += g1 * a.w;
  }
  ((float4*)out)[(size_t)t * (D_DIM / 4) + d] = v;
}

// ---------------- aux: stage 1 (64 blocks, one per (g,e)) ----------------
__global__ __launch_bounds__(256)
void aux1_kernel(const float* __restrict__ gates, float* __restrict__ imp) {
  const int g = blockIdx.x >> 3, e = blockIdx.x & 7;
  const int tid = threadIdx.x, lane = tid & 63, wave = tid >> 6;
  float s = 0.f;
  for (int t = tid; t < GRP_SZ; t += 256)
    s += gates[((size_t)g * GRP_SZ + t) * 8 + e];
#pragma unroll
  for (int off = 32; off > 0; off >>= 1) s += __shfl_xor(s, off, 64);
  __shared__ float ws4[4];
  if (lane == 0) ws4[wave] = s;
  __syncthreads();
  if (tid == 0) imp[blockIdx.x] = ws4[0] + ws4[1] + ws4[2] + ws4[3];
}

// ---------------- aux: stage 2 (tiny) ----------------
__global__ void aux2_kernel(const float* __restrict__ imp, float* __restrict__ aux_out) {
  const int t = threadIdx.x;  // 64
  __shared__ float cvS[8];
  if (t < 8) {
    float mean = 0.f;
    for (int k = 0; k < 8; k++) mean += imp[t * 8 + k];
    mean *= 0.125f;
    float var = 0.f;
    for (int k = 0; k < 8; k++) { float dd = imp[t * 8 + k] - mean; var += dd * dd; }
    var *= 0.125f;
    cvS[t] = var / (mean * mean);
  }
  __syncthreads();
  if (t == 0) {
    float a = 0.f;
    for (int k = 0; k < 8; k++) a += cvS[k];
    aux_out[0] = a * 0.125f;
  }
}

extern "C" void kernel_launch(void* const* d_in, const int* in_sizes, int n_in,
                              void* d_out, int out_size, void* d_ws, size_t ws_size,
                              hipStream_t stream) {
  const float* x  = (const float*)d_in[0];
  const float* wr = (const float*)d_in[1];
  const float* w1 = (const float*)d_in[2];
  const float* b1 = (const float*)d_in[3];
  const float* w2 = (const float*)d_in[4];
  const float* b2 = (const float*)d_in[5];
  float* out = (float*)d_out;

  char* ws = (char*)d_ws;
  size_t off = 0;
  auto alloc = [&](size_t bytes) -> void* {
    void* p = ws + off;
    off += (bytes + 255) & ~(size_t)255;
    return p;
  };
  float*     gates      = (float*)alloc((size_t)N_TOK * 8 * 4);
  int*       tk_idx     = (int*)  alloc((size_t)N_TOK * 2 * 4);
  float*     tk_val     = (float*)alloc((size_t)N_TOK * 2 * 4);
  int*       assign_row = (int*)  alloc((size_t)N_TOK * 2 * 4);
  int*       slot_src   = (int*)  alloc((size_t)SLOT_ROWS * 4);
  float*     imp        = (float*)alloc(64 * 4);
  _Float16*  A1  = (_Float16*)alloc((size_t)SLOT_ROWS * D_DIM * 2);
  _Float16*  w1t = (_Float16*)alloc((size_t)E_EXP * M_DIM * D_DIM * 2);
  _Float16*  w2t = (_Float16*)alloc((size_t)E_EXP * D_DIM * M_DIM * 2);
  _Float16*  H   = (_Float16*)alloc((size_t)SLOT_ROWS * M_DIM * 2);
  float*     ye  = (float*)   alloc((size_t)SLOT_ROWS * D_DIM * 4);
  if (off > ws_size) return;

  router_kernel<<<N_TOK / 4, 256, 0, stream>>>(x, wr, gates, tk_idx, tk_val);
  scan_kernel<<<N_GRP, 64, 0, stream>>>(tk_idx, slot_src, assign_row);
  gather_kernel<<<SLOT_ROWS, 256, 0, stream>>>(x, slot_src, A1);
  transpose_both_kernel<<<dim3(4096, 16), 256, 0, stream>>>(w1, w2, w1t, w2t);
  gemm256_kernel<D_DIM, M_DIM, 1>
      <<<dim3((ROWS_PER_E / 256) * (M_DIM / 256), 1, E_EXP), 512, 131072, stream>>>(A1, w1t, b1, H);
  gemm256_kernel<M_DIM, D_DIM, 2>
      <<<dim3((ROWS_PER_E / 256) * (D_DIM / 256), 1, E_EXP), 512, 131072, stream>>>(H, w2t, b2, ye);
  combine_kernel<<<N_TOK, 256, 0, stream>>>(ye, assign_row, tk_val, out);
  aux1_kernel<<<64, 256, 0, stream>>>(gates, imp);
  aux2_kernel<<<1, 64, 0, stream>>>(imp, out + (size_t)N_TOK * D_DIM);
}